// Round 10
// baseline (148.837 us; speedup 1.0000x reference)
//
#include <hip/hip_runtime.h>
#include <stdint.h>

#define H 384
#define W 384
#define C 19
#define NB 4
#define HW (H * W)
#define CHW (C * HW)
#define TOTAL_TERMS 47279376.0f   // NB * 81 * 382*382

#define NWP 14                // window-pairs per row; windows k=2wp+wi, x0=14k
#define NTASK (NB * NWP * 64) // 3584 wave-tasks (64 y-blocks of 6 rows)
#define NBLK (NTASK / 4)      // 896 blocks

typedef short    bf16x8 __attribute__((ext_vector_type(8)));
typedef float    f32x4  __attribute__((ext_vector_type(4)));
typedef uint32_t u32;

// number of kernel-offsets a in [0,2] with 0 <= a+d <= 2 and 0 <= p-a <= 381
__device__ __forceinline__ int multv(int p, int d) {
    int lo = max(max(0, -d), p - (H - 3));
    int hi = min(min(2, 2 - d), p);
    return max(0, hi - lo + 1);
}

__device__ __forceinline__ float bce_fast(float x, float y) {
    float t = __expf(-fabsf(x));
    return fmaxf(x, 0.0f) - x * y + __logf(1.0f + t);
}

// Wave-task = (n, window-pair wp, y-block of 6 rows). Per row y' the wave
// holds ONE fragment per window: 16 px (lane&15) x 32 ch (8*(lane>>4)+e,
// ch>=19 zero-padded) as bf16x8 — serves as BOTH mfma A and B operand.
// Tiles: D = mfma(frag[row y], frag[row y+dy]) gives all 256 channel-dots;
// cell (i,j) = dot(px x0+i row y, px x0+j row y+dy). Count cell iff
// |j-i|<=2 && min(i,j)<14 (stride-14 windows partition all pairs).
// dy=0: ordered weight wy0*wx(xp,dx). dy>0: combined wyA*wx(xp,dx)+wyB*wx(xq,-dx).
// Interior windows: wx = 3-|dx| exactly. No LDS, no syncthreads.
__global__ __launch_bounds__(256) void aff_mfma(
        const float* __restrict__ logits,
        const int* __restrict__ labels,
        float* __restrict__ partial) {
    const int tid  = threadIdx.x;
    const int lane = tid & 63;
    const int wid  = tid >> 6;
    const int g    = lane >> 4;
    const int j    = lane & 15;     // B pixel / C col
    const int cb   = g * 8;         // channel base of this lane-group
    const int ib   = g * 4;         // C row base (m89 layout)

    // XCD chunk swizzle (896 = 8*112), then decode: 16 blocks per (n,wp)
    const int b     = blockIdx.x;
    const int b2    = (b & 7) * (NBLK / 8) + (b >> 3);
    const int blkIn = b2 & 15;
    const int nwp   = b2 >> 4;
    const int wp    = nwp % NWP;
    const int n     = nwp / NWP;
    const int y0    = (blkIn * 4 + wid) * 6;

    const float* src = logits + (size_t)n * CHW;
    const int*   lab = labels + (size_t)n * HW;

    const int x0w[2] = {14 * (2 * wp), 14 * (2 * wp + 1)};
    const int xc[2]  = {min(x0w[0] + j, W - 1), min(x0w[1] + j, W - 1)};

    bf16x8 rf[2][3];
    int    rl[2][3];

#define LOADF(wi, yrow, slot) {                                           \
    const int yr = min((yrow), H - 1);                                    \
    const float* pp = src + (size_t)yr * W + xc[wi];                      \
    float v[8];                                                           \
    _Pragma("unroll")                                                     \
    for (int e = 0; e < 8; ++e)                                           \
        v[e] = (cb + e < C) ? pp[(size_t)(cb + e) * HW] : 0.0f;           \
    union { bf16x8 f; u32 u[4]; } uf;                                     \
    _Pragma("unroll")                                                     \
    for (int q = 0; q < 4; ++q)                                           \
        asm("v_cvt_pk_bf16_f32 %0, %1, %2"                                \
            : "=v"(uf.u[q]) : "v"(v[2*q]), "v"(v[2*q+1]));                \
    rf[wi][slot] = uf.f;                                                  \
    rl[wi][slot] = lab[yr * W + xc[wi]]; }

// epilogue over the 4 C-regs of one tile
#define EPI(wi, D, sA, sB, dy, sBslot, EW) {                              \
    const int   lq = rl[wi][sBslot];                                      \
    const float fA = (float)(sA), fB = (float)(sB);                       \
    _Pragma("unroll")                                                     \
    for (int r = 0; r < 4; ++r) {                                         \
        const int i   = ib + r;                                           \
        const int dxv = j - i;                                            \
        const int adx = abs(dxv);                                         \
        float w;                                                          \
        if (EW) {                                                         \
            const int wxp = multv(x0w[wi] + i, dxv);                      \
            const int wxq = multv(x0w[wi] + j, -dxv);                     \
            w = ((dy) == 0) ? fA * (float)wxp                             \
                            : (fA * (float)wxp + fB * (float)wxq);        \
        } else {                                                          \
            w = (((dy) == 0) ? fA : (fA + fB)) * (float)(3 - adx);        \
        }                                                                 \
        if (adx <= 2 && min(i, j) < 14 && w != 0.0f) {                    \
            const float yv = (labA[wi][r] == lq) ? 1.0f : 0.0f;           \
            total += w * bce_fast(D[r], yv);                              \
        }                                                                 \
    } }

    // prologue: rows y0, y0+1 -> slots 0, 1
    LOADF(0, y0,     0) LOADF(1, y0,     0)
    LOADF(0, y0 + 1, 1) LOADF(1, y0 + 1, 1)

    float total = 0.0f;
    const f32x4 Z = {0.0f, 0.0f, 0.0f, 0.0f};

#pragma unroll 3
    for (int yy = 0; yy < 6; ++yy) {
        const int y  = y0 + yy;
        const int s0 = yy % 3, s1 = (yy + 1) % 3, s2 = (yy + 2) % 3;
        LOADF(0, y + 2, s2) LOADF(1, y + 2, s2)

        int labA[2][4];
#pragma unroll
        for (int wi = 0; wi < 2; ++wi)
#pragma unroll
            for (int r = 0; r < 4; ++r)
                labA[wi][r] = lab[y * W + min(x0w[wi] + ib + r, W - 1)];

        const int wy0 = multv(y, 0);
        const int wA1 = multv(y, 1), wB1 = multv(y + 1, -1);
        const int wA2 = multv(y, 2), wB2 = multv(y + 2, -2);

#pragma unroll
        for (int wi = 0; wi < 2; ++wi) {
            const bool ew = (wi == 0) ? (wp == 0) : (wp == NWP - 1);
            {   // dy = 0
                f32x4 D = __builtin_amdgcn_mfma_f32_16x16x32_bf16(
                              rf[wi][s0], rf[wi][s0], Z, 0, 0, 0);
                if (ew) { EPI(wi, D, wy0, 0, 0, s0, 1) }
                else    { EPI(wi, D, wy0, 0, 0, s0, 0) }
            }
            if (wA1 + wB1) {   // dy = 1
                f32x4 D = __builtin_amdgcn_mfma_f32_16x16x32_bf16(
                              rf[wi][s0], rf[wi][s1], Z, 0, 0, 0);
                if (ew) { EPI(wi, D, wA1, wB1, 1, s1, 1) }
                else    { EPI(wi, D, wA1, wB1, 1, s1, 0) }
            }
            if (wA2 + wB2) {   // dy = 2
                f32x4 D = __builtin_amdgcn_mfma_f32_16x16x32_bf16(
                              rf[wi][s0], rf[wi][s2], Z, 0, 0, 0);
                if (ew) { EPI(wi, D, wA2, wB2, 2, s2, 1) }
                else    { EPI(wi, D, wA2, wB2, 2, s2, 0) }
            }
        }
    }

    // per-wave reduce; waves fully independent (no barrier in kernel)
#pragma unroll
    for (int off = 32; off > 0; off >>= 1) total += __shfl_down(total, off, 64);
    if (lane == 0) partial[b2 * 4 + wid] = total;
}

__global__ __launch_bounds__(256) void reduce_final(
        const float* __restrict__ partial, int n, float* __restrict__ out) {
    float s = 0.0f;
    for (int i = threadIdx.x; i < n; i += 256) s += partial[i];
#pragma unroll
    for (int off = 32; off > 0; off >>= 1) s += __shfl_down(s, off, 64);
    __shared__ float sm[4];
    const int lane = threadIdx.x & 63, w = threadIdx.x >> 6;
    if (lane == 0) sm[w] = s;
    __syncthreads();
    if (threadIdx.x == 0)
        out[0] = (sm[0] + sm[1] + sm[2] + sm[3]) / TOTAL_TERMS;
}

extern "C" void kernel_launch(void* const* d_in, const int* in_sizes, int n_in,
                              void* d_out, int out_size, void* d_ws, size_t ws_size,
                              hipStream_t stream) {
    const float* logits = (const float*)d_in[0];
    const int*   labels = (const int*)d_in[1];
    float* out     = (float*)d_out;
    float* partial = (float*)d_ws;   // NTASK floats = 14336 B

    aff_mfma<<<NBLK, 256, 0, stream>>>(logits, labels, partial);
    reduce_final<<<1, 256, 0, stream>>>(partial, NTASK, out);
}

// Round 11
// 44.153 us; speedup vs baseline: 3.3709x; 3.3709x over previous
//
#include <hip/hip_runtime.h>

#define H 384
#define W 384
#define C 19
#define NB 4
#define HP 382               // H - K + 1
#define HW (H * W)
#define CHW (C * HW)
#define TOTAL_TERMS 47279376.0f   // NB * 81 * HP*HP

#define NBLOCKS 1152         // 147456 groups / 128

// number of kernel-offsets a in [0,2] with 0 <= a+d <= 2 and 0 <= p-a <= HP-1
__device__ __forceinline__ int multv(int p, int d) {
    int lo = max(max(0, -d), p - (HP - 1));
    int hi = min(min(2, 2 - d), p);
    return max(0, hi - lo + 1);
}

__device__ __forceinline__ float bce_fast(float x, float y) {
    // max(x,0) - x*y + log1p(exp(-|x|)), fast-math variant
    float t = __expf(-fabsf(x));
    return fmaxf(x, 0.0f) - x * y + __logf(1.0f + t);
}

// R4 structure + shuffle-halo. Each thread owns 4 px (one aligned float4).
// Right halo (cols px0+4,5) = lane+1's f4.xy via __shfl_down (lane 63:
// predicated 8B load). Left halo = aligned float2 at px0-2. Mid-wave row
// seams only pollute weight-0 terms (multv==0 for cols >= 384).
//   par = wid&1: 0 -> offsets (0,0),(0,1),(0,2),(2,-2..2)  [rows y, y+2]
//                1 -> offsets (1,-2..2)                    [rows y, y+1]
// Grid: 1152 blocks x 256 (128 groups/block), XCD-chunk swizzled.
__global__ __launch_bounds__(256) void affinity_partial(
        const float* __restrict__ logits,
        const int* __restrict__ labels,
        float* __restrict__ partial) {
    const int t    = threadIdx.x;
    const int lane = t & 63;
    const int wid  = t >> 6;
    const int par  = wid & 1;

    const int b   = blockIdx.x;
    const int blk = (b & 7) * (NBLOCKS / 8) + (b >> 3);   // XCD chunking
    const int g   = blk * 128 + (wid >> 1) * 64 + lane;
    const int px0 = (g % 96) * 4;
    const int rs  = g / 96;
    const int py  = rs % H;
    const int n   = rs / H;

    const int loff = min(px0, 2);                  // left f2 at px0-loff (8B-aligned)
    const int roff = min(px0 + 4, W - 2) - px0;    // lane-63 right f2 (8B-aligned)
    const int ro1  = (min(py + 1, H - 1) - py) * W;
    const int ro2  = (min(py + 2, H - 1) - py) * W;

    const float* p0 = logits + (size_t)n * CHW + (size_t)py * W + px0;
    const bool e63 = (lane == 63);

    float total = 0.0f;

    if (par == 0) {
        float acc[32];
#pragma unroll
        for (int k = 0; k < 32; ++k) acc[k] = 0.0f;

        for (int c = 0; c < C; ++c) {
            const float* pr = p0 + (size_t)c * HW;
            float4 r0 = *(const float4*)(pr);
            float4 r2 = *(const float4*)(pr + ro2);
            float2 l2 = *(const float2*)(pr + ro2 - loff);
            float2 rh0, rh2;
            rh0.x = __shfl_down(r0.x, 1, 64);
            rh0.y = __shfl_down(r0.y, 1, 64);
            rh2.x = __shfl_down(r2.x, 1, 64);
            rh2.y = __shfl_down(r2.y, 1, 64);
            if (e63) {
                rh0 = *(const float2*)(pr + roff);
                rh2 = *(const float2*)(pr + ro2 + roff);
            }

            const float a6[6] = {r0.x, r0.y, r0.z, r0.w, rh0.x, rh0.y};
            const float e8[8] = {l2.x, l2.y, r2.x, r2.y, r2.z, r2.w, rh2.x, rh2.y};
#pragma unroll
            for (int i = 0; i < 4; ++i) {
                const float s = a6[i];
                acc[i * 8 + 0] += s * s;            // (0,0)
                acc[i * 8 + 1] += s * a6[i + 1];    // (0,1)
                acc[i * 8 + 2] += s * a6[i + 2];    // (0,2)
#pragma unroll
                for (int dxi = 0; dxi < 5; ++dxi)   // (2, dxi-2)
                    acc[i * 8 + 3 + dxi] += s * e8[i + dxi];
            }
        }

        // ---- epilogue (R9-proven) ----
        const int x0c = max(0, px0 - 4);
        const int d1  = px0 - x0c;
        const int d2  = min(W - 4, px0 + 4) - x0c;
        const int* lb0 = labels + (size_t)n * HW + (size_t)py * W + x0c;

        int la[8], ler[12];
        *(int4*)&la[0]  = *(const int4*)(lb0 + d1);   // cols px0..px0+3
        *(int4*)&la[4]  = *(const int4*)(lb0 + d2);   // cols px0+4..px0+7
        *(int4*)&ler[0] = *(const int4*)(lb0 + ro2);
        *(int4*)&ler[4] = *(const int4*)(lb0 + ro2 + d1);
        *(int4*)&ler[8] = *(const int4*)(lb0 + ro2 + d2);

        const int wy0 = multv(py, 0);
        const int wy2 = multv(py, 2);
#pragma unroll
        for (int i = 0; i < 4; ++i) {
            const int px = px0 + i;
            int wx[5];
#pragma unroll
            for (int dxi = 0; dxi < 5; ++dxi) wx[dxi] = multv(px, dxi - 2);
            const int ls = la[i];
            total += (float)(wy0 * wx[2]) * bce_fast(acc[i * 8 + 0], 1.0f);
            total += 2.0f * (float)(wy0 * wx[3]) *
                     bce_fast(acc[i * 8 + 1], (ls == la[i + 1]) ? 1.0f : 0.0f);
            total += 2.0f * (float)(wy0 * wx[4]) *
                     bce_fast(acc[i * 8 + 2], (ls == la[i + 2]) ? 1.0f : 0.0f);
#pragma unroll
            for (int dxi = 0; dxi < 5; ++dxi)
                total += 2.0f * (float)(wy2 * wx[dxi]) *
                         bce_fast(acc[i * 8 + 3 + dxi],
                                  (ls == ler[2 + i + dxi]) ? 1.0f : 0.0f);
        }
    } else {
        float acc[20];
#pragma unroll
        for (int k = 0; k < 20; ++k) acc[k] = 0.0f;

        for (int c = 0; c < C; ++c) {
            const float* pr = p0 + (size_t)c * HW;
            float4 r0 = *(const float4*)(pr);
            float4 r1 = *(const float4*)(pr + ro1);
            float2 l1 = *(const float2*)(pr + ro1 - loff);
            float2 rh1;
            rh1.x = __shfl_down(r1.x, 1, 64);
            rh1.y = __shfl_down(r1.y, 1, 64);
            if (e63) rh1 = *(const float2*)(pr + ro1 + roff);

            const float b8[8] = {l1.x, l1.y, r1.x, r1.y, r1.z, r1.w, rh1.x, rh1.y};
            const float s4[4] = {r0.x, r0.y, r0.z, r0.w};
#pragma unroll
            for (int i = 0; i < 4; ++i) {
                const float s = s4[i];
#pragma unroll
                for (int dxi = 0; dxi < 5; ++dxi)   // (1, dxi-2)
                    acc[i * 5 + dxi] += s * b8[i + dxi];
            }
        }

        const int x0c = max(0, px0 - 4);
        const int d1  = px0 - x0c;
        const int d2  = min(W - 4, px0 + 4) - x0c;
        const int* lb0 = labels + (size_t)n * HW + (size_t)py * W + x0c;

        int la4[4], lbr[12];
        *(int4*)&la4[0] = *(const int4*)(lb0 + d1);
        *(int4*)&lbr[0] = *(const int4*)(lb0 + ro1);
        *(int4*)&lbr[4] = *(const int4*)(lb0 + ro1 + d1);
        *(int4*)&lbr[8] = *(const int4*)(lb0 + ro1 + d2);

        const int wy1 = multv(py, 1);
#pragma unroll
        for (int i = 0; i < 4; ++i) {
            const int px = px0 + i;
            int wx[5];
#pragma unroll
            for (int dxi = 0; dxi < 5; ++dxi) wx[dxi] = multv(px, dxi - 2);
            const int ls = la4[i];
#pragma unroll
            for (int dxi = 0; dxi < 5; ++dxi)
                total += 2.0f * (float)(wy1 * wx[dxi]) *
                         bce_fast(acc[i * 5 + dxi],
                                  (ls == lbr[2 + i + dxi]) ? 1.0f : 0.0f);
        }
    }

    // block reduction: wave shuffle then LDS across the 4 waves
#pragma unroll
    for (int off = 32; off > 0; off >>= 1) total += __shfl_down(total, off, 64);
    __shared__ float sm[4];
    if (lane == 0) sm[wid] = total;
    __syncthreads();
    if (t == 0)
        partial[blockIdx.x] = sm[0] + sm[1] + sm[2] + sm[3];
}

__global__ __launch_bounds__(256) void reduce_final(
        const float* __restrict__ partial, int n, float* __restrict__ out) {
    float s = 0.0f;
    for (int i = threadIdx.x; i < n; i += 256) s += partial[i];
#pragma unroll
    for (int off = 32; off > 0; off >>= 1) s += __shfl_down(s, off, 64);
    __shared__ float sm[4];
    const int lane = threadIdx.x & 63, wid = threadIdx.x >> 6;
    if (lane == 0) sm[wid] = s;
    __syncthreads();
    if (threadIdx.x == 0)
        out[0] = (sm[0] + sm[1] + sm[2] + sm[3]) / TOTAL_TERMS;
}

extern "C" void kernel_launch(void* const* d_in, const int* in_sizes, int n_in,
                              void* d_out, int out_size, void* d_ws, size_t ws_size,
                              hipStream_t stream) {
    const float* logits = (const float*)d_in[0];
    const int*   labels = (const int*)d_in[1];
    float* out     = (float*)d_out;
    float* partial = (float*)d_ws;   // 1152 floats

    affinity_partial<<<NBLOCKS, 256, 0, stream>>>(logits, labels, partial);
    reduce_final<<<1, 256, 0, stream>>>(partial, NBLOCKS, out);
}

// Round 12
// 28.360 us; speedup vs baseline: 5.2481x; 1.5569x over previous
//
#include <hip/hip_runtime.h>

#define H 384
#define W 384
#define C 19
#define NB 4
#define HP 382               // H - K + 1
#define HW (H * W)
#define CHW (C * HW)
#define TOTAL_TERMS 47279376.0f   // NB * 81 * HP*HP

#define NBLOCKS 1152         // 147456 groups / 128

// number of kernel-offsets a in [0,2] with 0 <= a+d <= 2 and 0 <= p-a <= HP-1
__device__ __forceinline__ int multv(int p, int d) {
    int lo = max(max(0, -d), p - (HP - 1));
    int hi = min(min(2, 2 - d), p);
    return max(0, hi - lo + 1);
}

__device__ __forceinline__ float bce_fast(float x, float y) {
    // max(x,0) - x*y + log1p(exp(-|x|)), fast-math variant
    float t = __expf(-fabsf(x));
    return fmaxf(x, 0.0f) - x * y + __logf(1.0f + t);
}

// R4/R9 structure + register software-pipeline (depth 2) on the channel loop.
// Wave parity (wid&1): par0 -> offsets (0,0),(0,1),(0,2),(2,-2..2)  [rows y,y+2; 5 f4/ch]
//                      par1 -> offsets (1,-2..2)                    [rows y,y+1; 4 f4/ch]
// 3-slot static rotation: step t loads channel t+2 into slot (t+2)%3 and
// computes channel t from slot t%3 (fully unrolled -> all indices static;
// WAR dep on the slot bounds register growth by design).
// Grid: 1152 blocks x 256 (128 groups/block), XCD-chunk swizzled.
__global__ __launch_bounds__(256) void affinity_partial(
        const float* __restrict__ logits,
        const int* __restrict__ labels,
        float* __restrict__ partial) {
    const int t    = threadIdx.x;
    const int lane = t & 63;
    const int wid  = t >> 6;
    const int par  = wid & 1;

    const int b   = blockIdx.x;
    const int blk = (b & 7) * (NBLOCKS / 8) + (b >> 3);   // XCD chunking
    const int g   = blk * 128 + (wid >> 1) * 64 + lane;
    const int px0 = (g % 96) * 4;
    const int rs  = g / 96;
    const int py  = rs % H;
    const int n   = rs / H;

    // f4 at +d1 -> cols px0..px0+3, +d2 -> px0+4..+7, +0 -> px0-4..-1.
    // Degenerate edge slots only feed weight-0 terms (multv==0 off-image).
    const int x0c = max(0, px0 - 4);
    const int d1  = px0 - x0c;                 // 0 or 4
    const int d2  = min(W - 4, px0 + 4) - x0c; // 4 or 8 (==d1 at right edge)
    const int ro1 = (min(py + 1, H - 1) - py) * W;
    const int ro2 = (min(py + 2, H - 1) - py) * W;

    const float* p0  = logits + (size_t)n * CHW + (size_t)py * W + x0c;
    const int*   lb0 = labels + (size_t)n * HW + (size_t)py * W + x0c;

    float total = 0.0f;

    if (par == 0) {
        float acc[32];
#pragma unroll
        for (int k = 0; k < 32; ++k) acc[k] = 0.0f;

        float4 sA1[3], sA2[3], sE0[3], sE1[3], sE2[3];

#define P0L(ch, sl) {                                                     \
        const float* pr = p0 + (size_t)(ch) * HW;                         \
        sA1[sl] = *(const float4*)(pr + d1);                              \
        sA2[sl] = *(const float4*)(pr + d2);                              \
        sE0[sl] = *(const float4*)(pr + ro2);                             \
        sE1[sl] = *(const float4*)(pr + ro2 + d1);                        \
        sE2[sl] = *(const float4*)(pr + ro2 + d2); }

#define P0C(sl) {                                                         \
        const float a6[6] = {sA1[sl].x, sA1[sl].y, sA1[sl].z, sA1[sl].w,  \
                             sA2[sl].x, sA2[sl].y};                       \
        const float e8[8] = {sE0[sl].z, sE0[sl].w,                        \
                             sE1[sl].x, sE1[sl].y, sE1[sl].z, sE1[sl].w,  \
                             sE2[sl].x, sE2[sl].y};                       \
        _Pragma("unroll")                                                 \
        for (int i = 0; i < 4; ++i) {                                     \
            const float s = a6[i];                                        \
            acc[i * 8 + 0] += s * s;                                      \
            acc[i * 8 + 1] += s * a6[i + 1];                              \
            acc[i * 8 + 2] += s * a6[i + 2];                              \
            _Pragma("unroll")                                             \
            for (int dxi = 0; dxi < 5; ++dxi)                             \
                acc[i * 8 + 3 + dxi] += s * e8[i + dxi];                  \
        } }

        P0L(0, 0) P0L(1, 1)
#pragma unroll
        for (int st = 0; st < 19; ++st) {
            if (st + 2 < 19) { P0L(st + 2, (st + 2) % 3) }
            P0C(st % 3)
        }

        int la[8], ler[12];
        *(int4*)&la[0]  = *(const int4*)(lb0 + d1);   // cols px0..px0+3
        *(int4*)&la[4]  = *(const int4*)(lb0 + d2);   // cols px0+4..px0+7
        *(int4*)&ler[0] = *(const int4*)(lb0 + ro2);
        *(int4*)&ler[4] = *(const int4*)(lb0 + ro2 + d1);
        *(int4*)&ler[8] = *(const int4*)(lb0 + ro2 + d2);

        const int wy0 = multv(py, 0);
        const int wy2 = multv(py, 2);
#pragma unroll
        for (int i = 0; i < 4; ++i) {
            const int px = px0 + i;
            int wx[5];
#pragma unroll
            for (int dxi = 0; dxi < 5; ++dxi) wx[dxi] = multv(px, dxi - 2);
            const int ls = la[i];
            total += (float)(wy0 * wx[2]) * bce_fast(acc[i * 8 + 0], 1.0f);
            total += 2.0f * (float)(wy0 * wx[3]) *
                     bce_fast(acc[i * 8 + 1], (ls == la[i + 1]) ? 1.0f : 0.0f);
            total += 2.0f * (float)(wy0 * wx[4]) *
                     bce_fast(acc[i * 8 + 2], (ls == la[i + 2]) ? 1.0f : 0.0f);
#pragma unroll
            for (int dxi = 0; dxi < 5; ++dxi)
                total += 2.0f * (float)(wy2 * wx[dxi]) *
                         bce_fast(acc[i * 8 + 3 + dxi],
                                  (ls == ler[2 + i + dxi]) ? 1.0f : 0.0f);
        }
    } else {
        float acc[20];
#pragma unroll
        for (int k = 0; k < 20; ++k) acc[k] = 0.0f;

        float4 sS[3], sB0[3], sB1[3], sB2[3];

#define P1L(ch, sl) {                                                     \
        const float* pr = p0 + (size_t)(ch) * HW;                         \
        sS[sl]  = *(const float4*)(pr + d1);                              \
        sB0[sl] = *(const float4*)(pr + ro1);                             \
        sB1[sl] = *(const float4*)(pr + ro1 + d1);                        \
        sB2[sl] = *(const float4*)(pr + ro1 + d2); }

#define P1C(sl) {                                                         \
        const float b8[8] = {sB0[sl].z, sB0[sl].w,                        \
                             sB1[sl].x, sB1[sl].y, sB1[sl].z, sB1[sl].w,  \
                             sB2[sl].x, sB2[sl].y};                       \
        const float s4[4] = {sS[sl].x, sS[sl].y, sS[sl].z, sS[sl].w};     \
        _Pragma("unroll")                                                 \
        for (int i = 0; i < 4; ++i) {                                     \
            const float s = s4[i];                                        \
            _Pragma("unroll")                                             \
            for (int dxi = 0; dxi < 5; ++dxi)                             \
                acc[i * 5 + dxi] += s * b8[i + dxi];                      \
        } }

        P1L(0, 0) P1L(1, 1)
#pragma unroll
        for (int st = 0; st < 19; ++st) {
            if (st + 2 < 19) { P1L(st + 2, (st + 2) % 3) }
            P1C(st % 3)
        }

        int la4[4], lbr[12];
        *(int4*)&la4[0] = *(const int4*)(lb0 + d1);
        *(int4*)&lbr[0] = *(const int4*)(lb0 + ro1);
        *(int4*)&lbr[4] = *(const int4*)(lb0 + ro1 + d1);
        *(int4*)&lbr[8] = *(const int4*)(lb0 + ro1 + d2);

        const int wy1 = multv(py, 1);
#pragma unroll
        for (int i = 0; i < 4; ++i) {
            const int px = px0 + i;
            int wx[5];
#pragma unroll
            for (int dxi = 0; dxi < 5; ++dxi) wx[dxi] = multv(px, dxi - 2);
            const int ls = la4[i];
#pragma unroll
            for (int dxi = 0; dxi < 5; ++dxi)
                total += 2.0f * (float)(wy1 * wx[dxi]) *
                         bce_fast(acc[i * 5 + dxi],
                                  (ls == lbr[2 + i + dxi]) ? 1.0f : 0.0f);
        }
    }

    // block reduction: wave shuffle then LDS across the 4 waves
#pragma unroll
    for (int off = 32; off > 0; off >>= 1) total += __shfl_down(total, off, 64);
    __shared__ float sm[4];
    if (lane == 0) sm[wid] = total;
    __syncthreads();
    if (t == 0)
        partial[blockIdx.x] = sm[0] + sm[1] + sm[2] + sm[3];
}

__global__ __launch_bounds__(256) void reduce_final(
        const float* __restrict__ partial, int n, float* __restrict__ out) {
    float s = 0.0f;
    for (int i = threadIdx.x; i < n; i += 256) s += partial[i];
#pragma unroll
    for (int off = 32; off > 0; off >>= 1) s += __shfl_down(s, off, 64);
    __shared__ float sm[4];
    const int lane = threadIdx.x & 63, wid = threadIdx.x >> 6;
    if (lane == 0) sm[wid] = s;
    __syncthreads();
    if (threadIdx.x == 0)
        out[0] = (sm[0] + sm[1] + sm[2] + sm[3]) / TOTAL_TERMS;
}

extern "C" void kernel_launch(void* const* d_in, const int* in_sizes, int n_in,
                              void* d_out, int out_size, void* d_ws, size_t ws_size,
                              hipStream_t stream) {
    const float* logits = (const float*)d_in[0];
    const int*   labels = (const int*)d_in[1];
    float* out     = (float*)d_out;
    float* partial = (float*)d_ws;   // 1152 floats

    affinity_partial<<<NBLOCKS, 256, 0, stream>>>(logits, labels, partial);
    reduce_final<<<1, 256, 0, stream>>>(partial, NBLOCKS, out);
}